// Round 1
// baseline (612.490 us; speedup 1.0000x reference)
//
#include <hip/hip_runtime.h>
#include <math.h>

#define B_ 64
#define P_ 25
#define D_ 128
#define T_ 120
#define L_ 2
#define K_ 4
#define LN_EPS 1e-5f

// One block per (b,t): build kNN row-wise adjacency (row degree is always
// K+1=5, so normalized A = adj/5), then 2 fused GCN layers entirely in LDS.
// Thread = feature column d (128 threads). h values in the GEMM are
// wave-uniform LDS broadcasts; W reads are coalesced and L2-resident.
__global__ __launch_bounds__(128) void gcn_fused(
    const float* __restrict__ x,       // [B,P,D,T]
    const float* __restrict__ dist,    // [B,T,P,P]
    const float* __restrict__ weights, // [L,D,D]
    const float* __restrict__ biases,  // [L,D]
    const float* __restrict__ gamma,   // [L,D]
    const float* __restrict__ beta,    // [L,D]
    float* __restrict__ out)           // [B,P,D,T]
{
    // t-swizzle: keep 15 consecutive t on the same XCD (blockIdx%8 round-robin)
    const int u = blockIdx.x;              // 0..119
    const int t = (u & 7) * 15 + (u >> 3); // bijective on [0,120)
    const int b = blockIdx.y;
    const int d = threadIdx.x;             // 0..127

    __shared__ __align__(16) float h_lds[P_][D_];
    __shared__ __align__(16) float y_lds[P_][D_];
    __shared__ int   nbr[P_][K_];
    __shared__ float mu_s[P_], rs_s[P_];

    // ---- load x slice (fixed t): h[p][d] = x[b,p,d,t] ----
    {
        const float* xb = x + (size_t)b * P_ * D_ * T_ + t;
        #pragma unroll
        for (int p = 0; p < P_; ++p)
            h_lds[p][d] = xb[(size_t)(p * D_ + d) * T_];
    }

    // ---- kNN selection: thread p<25 finds its 4 nearest (tie -> lower idx) ----
    if (d < P_) {
        const int p = d;
        const float* drow = dist + (((size_t)b * T_ + t) * P_ + p) * P_;
        float dr[P_];
        #pragma unroll
        for (int q = 0; q < P_; ++q) dr[q] = drow[q];
        dr[p] = 1e30f;  // mask self (reference adds 1e10 on diagonal)
        unsigned chosen = 0u;
        #pragma unroll
        for (int j = 0; j < K_; ++j) {
            float best = 1e29f; int bi = 0;
            #pragma unroll
            for (int q = 0; q < P_; ++q) {
                // strict < => first (lowest) index wins ties, matching lax.top_k
                if (!((chosen >> q) & 1u) && dr[q] < best) { best = dr[q]; bi = q; }
            }
            chosen |= 1u << bi;
            nbr[p][j] = bi;
        }
    }
    __syncthreads();

    for (int l = 0; l < L_; ++l) {
        const float* W = weights + (size_t)l * D_ * D_;

        // ---- y = h @ W : thread d owns column d, acc over all 25 rows ----
        float acc[P_];
        #pragma unroll
        for (int p = 0; p < P_; ++p) acc[p] = 0.f;

        for (int e0 = 0; e0 < D_; e0 += 8) {
            float w0 = W[(e0 + 0) * D_ + d];
            float w1 = W[(e0 + 1) * D_ + d];
            float w2 = W[(e0 + 2) * D_ + d];
            float w3 = W[(e0 + 3) * D_ + d];
            float w4 = W[(e0 + 4) * D_ + d];
            float w5 = W[(e0 + 5) * D_ + d];
            float w6 = W[(e0 + 6) * D_ + d];
            float w7 = W[(e0 + 7) * D_ + d];
            #pragma unroll
            for (int p = 0; p < P_; ++p) {
                const float4 ha = *(const float4*)&h_lds[p][e0];     // broadcast
                const float4 hb = *(const float4*)&h_lds[p][e0 + 4]; // broadcast
                acc[p] += ha.x * w0 + ha.y * w1 + ha.z * w2 + ha.w * w3
                        + hb.x * w4 + hb.y * w5 + hb.z * w6 + hb.w * w7;
            }
        }
        #pragma unroll
        for (int p = 0; p < P_; ++p) y_lds[p][d] = acc[p];
        __syncthreads();

        // ---- z = relu(adj/5 @ y + bias) into registers ----
        const float bs = biases[l * D_ + d];
        float z[P_];
        #pragma unroll
        for (int p = 0; p < P_; ++p) {
            float s = y_lds[p][d];
            s += y_lds[nbr[p][0]][d];
            s += y_lds[nbr[p][1]][d];
            s += y_lds[nbr[p][2]][d];
            s += y_lds[nbr[p][3]][d];
            s = s * 0.2f + bs;
            z[p] = fmaxf(s, 0.f);
        }
        __syncthreads();
        // stash z for the LN reduction (reuse y buffer)
        #pragma unroll
        for (int p = 0; p < P_; ++p) y_lds[p][d] = z[p];
        __syncthreads();

        // ---- LN stats: thread p reduces row p with diagonal offset
        //      (bank = (i+5p)%32, distinct per p -> conflict-free) ----
        if (d < P_) {
            const int p = d;
            float s = 0.f, s2 = 0.f;
            for (int i = 0; i < D_; ++i) {
                const int ii = (i + p * 5) & (D_ - 1);
                const float v = y_lds[p][ii];
                s += v; s2 += v * v;
            }
            const float mu  = s * (1.f / D_);
            const float var = s2 * (1.f / D_) - mu * mu;
            mu_s[p] = mu;
            rs_s[p] = rsqrtf(var + LN_EPS);
        }
        __syncthreads();

        // ---- apply LN affine + residual into h ----
        const float g  = gamma[l * D_ + d];
        const float be = beta[l * D_ + d];
        #pragma unroll
        for (int p = 0; p < P_; ++p) {
            const float v = (z[p] - mu_s[p]) * rs_s[p] * g + be;
            h_lds[p][d] += v;
        }
        __syncthreads();
    }

    // ---- store: out[b,p,d,t] = h[p][d] ----
    {
        float* ob = out + (size_t)b * P_ * D_ * T_ + t;
        #pragma unroll
        for (int p = 0; p < P_; ++p)
            ob[(size_t)(p * D_ + d) * T_] = h_lds[p][d];
    }
}

extern "C" void kernel_launch(void* const* d_in, const int* in_sizes, int n_in,
                              void* d_out, int out_size, void* d_ws, size_t ws_size,
                              hipStream_t stream) {
    const float* x     = (const float*)d_in[0];
    const float* dist  = (const float*)d_in[1];
    const float* w     = (const float*)d_in[2];
    const float* bias  = (const float*)d_in[3];
    const float* gam   = (const float*)d_in[4];
    const float* bet   = (const float*)d_in[5];
    float* out = (float*)d_out;

    dim3 grid(T_, B_);
    gcn_fused<<<grid, dim3(128), 0, stream>>>(x, dist, w, bias, gam, bet, out);
}

// Round 3
// 418.497 us; speedup vs baseline: 1.4635x; 1.4635x over previous
//
#include <hip/hip_runtime.h>
#include <math.h>

#define B_ 64
#define P_ 25
#define D_ 128
#define T_ 120
#define L_ 2
#define K_ 4
#define GT 4                  // t-slices per block (1 per wave)
#define LN_EPS 1e-5f
#define HSTRF 132             // fp32 LDS row stride: 16B-aligned, %32==4 -> <=2-way banks

typedef __attribute__((ext_vector_type(8))) _Float16 half8;  // MFMA A/B frag
typedef __attribute__((ext_vector_type(4))) float f4v;       // MFMA accumulator

// Pre-swizzle W[l][k][n] (fp32) into per-lane fp16 B-fragments:
// wf[(((l*8+nt)*4+ks)*64+lane)*8 + j] = f16( W[l][ks*32+(lane>>4)*8+j][nt*16+(lane&15)] )
__global__ __launch_bounds__(256) void pack_w(const float* __restrict__ W,
                                              _Float16* __restrict__ wf) {
    int id = blockIdx.x * 256 + threadIdx.x;          // 0..4095
    int lane = id & 63, rest = id >> 6;
    int ks = rest & 3, nt = (rest >> 2) & 7, l = rest >> 5;
    int n  = nt * 16 + (lane & 15);
    int kb = ks * 32 + (lane >> 4) * 8;
    _Float16 v[8];
    for (int j = 0; j < 8; ++j)
        v[j] = (_Float16)W[((size_t)l * D_ + kb + j) * D_ + n];
    *reinterpret_cast<half8*>(wf + (size_t)id * 8) = *reinterpret_cast<half8*>(v);
}

// One block per (b, 4 consecutive t); wave w owns t-slice w.
// h kept fp32 in LDS. Uses adj@(h@W) == (adj@h)@W: the neighbor mix (exact
// fp32) happens while building A-fragments; y never touches LDS. GEMM is
// split-precision fp16 (a_hi + a_lo), so only W's fp16 rounding remains.
__global__ __launch_bounds__(256) void gcn_mfma(
    const float* __restrict__ x,       // [B,P,D,T]
    const float* __restrict__ dist,    // [B,T,P,P]
    const _Float16* __restrict__ wf,   // packed fp16 W fragments
    const float* __restrict__ biases,  // [L,D]
    const float* __restrict__ gamma,   // [L,D]
    const float* __restrict__ beta,    // [L,D]
    float* __restrict__ out)           // [B,P,D,T]
{
    const int tg = blockIdx.x, b = blockIdx.y;
    const int t0 = tg * GT;
    const int tid = threadIdx.x;
    const int wave = tid >> 6, lane = tid & 63;

    __shared__ __align__(16) float h_lds[GT][P_][HSTRF];  // fp32 h
    __shared__ int nbr[GT][P_][4];

    // ---- load x -> h fp32 (float4 across the 4 t's: 16B-dense) ----
    {
        const float* xb = x + (size_t)b * P_ * D_ * T_ + t0;
        for (int i = tid; i < P_ * D_; i += 256) {
            int p = i >> 7, d = i & 127;
            float4 v = *reinterpret_cast<const float4*>(xb + (size_t)i * T_);
            h_lds[0][p][d] = v.x;
            h_lds[1][p][d] = v.y;
            h_lds[2][p][d] = v.z;
            h_lds[3][p][d] = v.w;
        }
    }

    // ---- kNN from global dist (L2-hot). Row degree always K+1=5 -> adj = A/5.
    if (tid < GT * P_) {
        int tt = tid / P_, p = tid % P_;
        const float* drow = dist + (((size_t)b * T_ + t0 + tt) * P_ + p) * P_;
        float dr[P_];
        #pragma unroll
        for (int q = 0; q < P_; ++q) dr[q] = drow[q];
        dr[p] = 1e30f;
        unsigned chosen = 0;
        #pragma unroll
        for (int j = 0; j < K_; ++j) {
            float best = 1e29f; int bi = 0;
            #pragma unroll
            for (int q = 0; q < P_; ++q)   // strict < -> lowest index wins ties
                if (!((chosen >> q) & 1u) && dr[q] < best) { best = dr[q]; bi = q; }
            chosen |= 1u << bi;
            nbr[tt][p][j] = bi;
        }
    }
    __syncthreads();

    const int t = wave;
    const int m = lane & 15, quad = lane >> 4;
    const int mB = m + 16;
    const bool vB = (mB < P_);
    const int  prB = vB ? mB : 0;
    const float scB = vB ? 0.2f : 0.0f;   // zero out padded rows 25..31
    const float* hb = &h_lds[t][0][0];
    const int4 nb0 = *reinterpret_cast<const int4*>(&nbr[t][m][0]);
    const int4 nb1 = *reinterpret_cast<const int4*>(&nbr[t][prB][0]);

    for (int l = 0; l < L_; ++l) {
        f4v acc[8][2];
        #pragma unroll
        for (int nt = 0; nt < 8; ++nt) {
            acc[nt][0] = (f4v){0.f, 0.f, 0.f, 0.f};
            acc[nt][1] = (f4v){0.f, 0.f, 0.f, 0.f};
        }
        const _Float16* wfl = wf + (size_t)l * 8 * 4 * 64 * 8;

        #pragma unroll
        for (int ks = 0; ks < 4; ++ks) {
            const int ko = ks * 32 + quad * 8;
            // ---- g = 0.2*(h[row] + sum of 4 nbr rows), exact fp32 ----
            float g0[8], g1[8];
            {
                const float* r  = hb + m     * HSTRF + ko;
                const float* n0 = hb + nb0.x * HSTRF + ko;
                const float* n1 = hb + nb0.y * HSTRF + ko;
                const float* n2 = hb + nb0.z * HSTRF + ko;
                const float* n3 = hb + nb0.w * HSTRF + ko;
                #pragma unroll
                for (int j = 0; j < 8; ++j)
                    g0[j] = 0.2f * (r[j] + n0[j] + n1[j] + n2[j] + n3[j]);
            }
            {
                const float* r  = hb + prB   * HSTRF + ko;
                const float* n0 = hb + nb1.x * HSTRF + ko;
                const float* n1 = hb + nb1.y * HSTRF + ko;
                const float* n2 = hb + nb1.z * HSTRF + ko;
                const float* n3 = hb + nb1.w * HSTRF + ko;
                #pragma unroll
                for (int j = 0; j < 8; ++j)
                    g1[j] = scB * (r[j] + n0[j] + n1[j] + n2[j] + n3[j]);
            }
            // ---- split-precision fp16 fragments: g ~= hi + lo (22-bit mantissa)
            half8 ahi0, alo0, ahi1, alo1;
            #pragma unroll
            for (int j = 0; j < 8; ++j) {
                _Float16 h0 = (_Float16)g0[j];
                ahi0[j] = h0; alo0[j] = (_Float16)(g0[j] - (float)h0);
                _Float16 h1 = (_Float16)g1[j];
                ahi1[j] = h1; alo1[j] = (_Float16)(g1[j] - (float)h1);
            }
            #pragma unroll
            for (int nt = 0; nt < 8; ++nt) {
                half8 bf = *reinterpret_cast<const half8*>(
                    wfl + (size_t)((nt * 4 + ks) * 64 + lane) * 8);  // coalesced, L2-hot
                acc[nt][0] = __builtin_amdgcn_mfma_f32_16x16x32_f16(ahi0, bf, acc[nt][0], 0, 0, 0);
                acc[nt][0] = __builtin_amdgcn_mfma_f32_16x16x32_f16(alo0, bf, acc[nt][0], 0, 0, 0);
                acc[nt][1] = __builtin_amdgcn_mfma_f32_16x16x32_f16(ahi1, bf, acc[nt][1], 0, 0, 0);
                acc[nt][1] = __builtin_amdgcn_mfma_f32_16x16x32_f16(alo1, bf, acc[nt][1], 0, 0, 0);
            }
        }

        // ---- epilogue in registers: bias + relu + LN + residual into h ----
        float bsv[8], gmv[8], btv[8];
        #pragma unroll
        for (int nt = 0; nt < 8; ++nt) {
            int c = l * D_ + nt * 16 + m;
            bsv[nt] = biases[c]; gmv[nt] = gamma[c]; btv[nt] = beta[c];
        }
        // C layout: col = nt*16 + (lane&15), row = mt*16 + quad*4 + r.
        // A row's 128 cols live in the 16 lanes of one quad -> xor 1,2,4,8.
        #pragma unroll
        for (int mt = 0; mt < 2; ++mt) {
            #pragma unroll
            for (int r = 0; r < 4; ++r) {
                const int mm = mt * 16 + quad * 4 + r;
                float z[8], s = 0.f, s2 = 0.f;
                #pragma unroll
                for (int nt = 0; nt < 8; ++nt) {
                    float zz = fmaxf(acc[nt][mt][r] + bsv[nt], 0.f);
                    z[nt] = zz; s += zz; s2 += zz * zz;
                }
                #pragma unroll
                for (int o = 1; o < 16; o <<= 1) {   // reduce within quad (16 lanes)
                    s  += __shfl_xor(s, o);
                    s2 += __shfl_xor(s2, o);
                }
                if (mm < P_) {
                    float mu  = s * (1.f / 128.f);
                    float var = s2 * (1.f / 128.f) - mu * mu;
                    float rs  = rsqrtf(var + LN_EPS);
                    #pragma unroll
                    for (int nt = 0; nt < 8; ++nt)
                        h_lds[t][mm][nt * 16 + m] += (z[nt] - mu) * rs * gmv[nt] + btv[nt];
                }
            }
        }
        __syncthreads();   // cross-lane h visibility for next layer / store
    }

    // ---- store: out[b,p,d,t0..t0+3] as float4 ----
    {
        float* ob = out + (size_t)b * P_ * D_ * T_ + t0;
        for (int i = tid; i < P_ * D_; i += 256) {
            int p = i >> 7, d = i & 127;
            float4 v;
            v.x = h_lds[0][p][d];
            v.y = h_lds[1][p][d];
            v.z = h_lds[2][p][d];
            v.w = h_lds[3][p][d];
            *reinterpret_cast<float4*>(ob + (size_t)i * T_) = v;
        }
    }
}

extern "C" void kernel_launch(void* const* d_in, const int* in_sizes, int n_in,
                              void* d_out, int out_size, void* d_ws, size_t ws_size,
                              hipStream_t stream) {
    const float* x    = (const float*)d_in[0];
    const float* dist = (const float*)d_in[1];
    const float* w    = (const float*)d_in[2];
    const float* bias = (const float*)d_in[3];
    const float* gam  = (const float*)d_in[4];
    const float* bet  = (const float*)d_in[5];
    float* out = (float*)d_out;
    _Float16* wf = (_Float16*)d_ws;   // 2*8*4*64*8 fp16 = 64KB

    pack_w<<<16, 256, 0, stream>>>(w, wf);
    gcn_mfma<<<dim3(T_ / GT, B_), 256, 0, stream>>>(x, dist, wf, bias, gam, bet, out);
}

// Round 4
// 378.336 us; speedup vs baseline: 1.6189x; 1.1062x over previous
//
#include <hip/hip_runtime.h>
#include <math.h>

#define B_ 64
#define P_ 25
#define D_ 128
#define T_ 120
#define L_ 2
#define K_ 4
#define GT 4                  // t-slices per block (1 per wave)
#define LN_EPS 1e-5f
#define HSTRF 132             // fp32 LDS row stride: 16B-aligned, %32==4 -> <=2-way banks

typedef __attribute__((ext_vector_type(8))) _Float16 half8;  // MFMA A/B frag
typedef __attribute__((ext_vector_type(4))) float f4v;       // MFMA accumulator

// Pre-swizzle W[l][k][n] (fp32) into per-lane fp16 B-fragments:
// wf[(((l*8+nt)*4+ks)*64+lane)*8 + j] = f16( W[l][ks*32+(lane>>4)*8+j][nt*16+(lane&15)] )
__global__ __launch_bounds__(256) void pack_w(const float* __restrict__ W,
                                              _Float16* __restrict__ wf) {
    int id = blockIdx.x * 256 + threadIdx.x;          // 0..4095
    int lane = id & 63, rest = id >> 6;
    int ks = rest & 3, nt = (rest >> 2) & 7, l = rest >> 5;
    int n  = nt * 16 + (lane & 15);
    int kb = ks * 32 + (lane >> 4) * 8;
    _Float16 v[8];
    for (int j = 0; j < 8; ++j)
        v[j] = (_Float16)W[((size_t)l * D_ + kb + j) * D_ + n];
    *reinterpret_cast<half8*>(wf + (size_t)id * 8) = *reinterpret_cast<half8*>(v);
}

// One block per (b, 4 consecutive t); wave w owns t-slice w.
// Grid is (b fastest, tg second): t-adjacent blocks differ by 64 in linear id
// == 0 mod 8 -> same XCD -> the 64B x/out lines (16 t's, 4 blocks) are L2-shared.
// h kept fp32 in LDS; mix-before-GEMM (adj@(h@W) == (adj@h)@W) in exact fp32;
// split-precision fp16 GEMM (a_hi+a_lo) leaves only W's fp16 rounding.
// LDS trimmed to 53.2KB -> 3 blocks/CU (12 waves) instead of 2.
__global__ __launch_bounds__(256) void gcn_mfma(
    const float* __restrict__ x,       // [B,P,D,T]
    const float* __restrict__ dist,    // [B,T,P,P]
    const _Float16* __restrict__ wf,   // packed fp16 W fragments
    const float* __restrict__ biases,  // [L,D]
    const float* __restrict__ gamma,   // [L,D]
    const float* __restrict__ beta,    // [L,D]
    float* __restrict__ out)           // [B,P,D,T]
{
    const int b = blockIdx.x, tg = blockIdx.y;
    const int t0 = tg * GT;
    const int tid = threadIdx.x;
    const int wave = tid >> 6, lane = tid & 63;

    __shared__ __align__(16) float h_lds[GT][P_][HSTRF];  // fp32 h (52.8 KB)
    __shared__ unsigned char nbr[GT][P_][4];              // 400 B

    // ---- load x -> h fp32 (float4 across the 4 t's: 16B-dense) ----
    {
        const float* xb = x + (size_t)b * P_ * D_ * T_ + t0;
        for (int i = tid; i < P_ * D_; i += 256) {
            int p = i >> 7, d = i & 127;
            float4 v = *reinterpret_cast<const float4*>(xb + (size_t)i * T_);
            h_lds[0][p][d] = v.x;
            h_lds[1][p][d] = v.y;
            h_lds[2][p][d] = v.z;
            h_lds[3][p][d] = v.w;
        }
    }

    // ---- kNN from global dist (L2-hot). Row degree always K+1=5 -> adj = A/5.
    if (tid < GT * P_) {
        int tt = tid / P_, p = tid % P_;
        const float* drow = dist + (((size_t)b * T_ + t0 + tt) * P_ + p) * P_;
        float dr[P_];
        #pragma unroll
        for (int q = 0; q < P_; ++q) dr[q] = drow[q];
        dr[p] = 1e30f;
        unsigned chosen = 0;
        #pragma unroll
        for (int j = 0; j < K_; ++j) {
            float best = 1e29f; int bi = 0;
            #pragma unroll
            for (int q = 0; q < P_; ++q)   // strict < -> lowest index wins ties
                if (!((chosen >> q) & 1u) && dr[q] < best) { best = dr[q]; bi = q; }
            chosen |= 1u << bi;
            nbr[tt][p][j] = (unsigned char)bi;
        }
    }
    __syncthreads();

    const int t = wave;
    const int m = lane & 15, quad = lane >> 4;
    const int mB = m + 16;
    const bool vB = (mB < P_);
    const int  prB = vB ? mB : 0;
    const float scB = vB ? 0.2f : 0.0f;   // zero out padded rows 25..31
    const float* hb = &h_lds[t][0][0];
    const uchar4 nb0 = *reinterpret_cast<const uchar4*>(&nbr[t][m][0]);
    const uchar4 nb1 = *reinterpret_cast<const uchar4*>(&nbr[t][prB][0]);
    const int n00 = nb0.x, n01 = nb0.y, n02 = nb0.z, n03 = nb0.w;
    const int n10 = nb1.x, n11 = nb1.y, n12 = nb1.z, n13 = nb1.w;

    for (int l = 0; l < L_; ++l) {
        f4v acc[8][2];
        #pragma unroll
        for (int nt = 0; nt < 8; ++nt) {
            acc[nt][0] = (f4v){0.f, 0.f, 0.f, 0.f};
            acc[nt][1] = (f4v){0.f, 0.f, 0.f, 0.f};
        }
        const _Float16* wfl = wf + (size_t)l * 8 * 4 * 64 * 8;

        #pragma unroll
        for (int ks = 0; ks < 4; ++ks) {
            const int ko = ks * 32 + quad * 8;
            // ---- g = 0.2*(h[row] + sum of 4 nbr rows), exact fp32 ----
            float g0[8], g1[8];
            {
                const float* r  = hb + m   * HSTRF + ko;
                const float* p0 = hb + n00 * HSTRF + ko;
                const float* p1 = hb + n01 * HSTRF + ko;
                const float* p2 = hb + n02 * HSTRF + ko;
                const float* p3 = hb + n03 * HSTRF + ko;
                #pragma unroll
                for (int j = 0; j < 8; ++j)
                    g0[j] = 0.2f * (r[j] + p0[j] + p1[j] + p2[j] + p3[j]);
            }
            {
                const float* r  = hb + prB * HSTRF + ko;
                const float* p0 = hb + n10 * HSTRF + ko;
                const float* p1 = hb + n11 * HSTRF + ko;
                const float* p2 = hb + n12 * HSTRF + ko;
                const float* p3 = hb + n13 * HSTRF + ko;
                #pragma unroll
                for (int j = 0; j < 8; ++j)
                    g1[j] = scB * (r[j] + p0[j] + p1[j] + p2[j] + p3[j]);
            }
            // ---- split-precision fp16 fragments: g ~= hi + lo (22-bit mantissa)
            half8 ahi0, alo0, ahi1, alo1;
            #pragma unroll
            for (int j = 0; j < 8; ++j) {
                _Float16 h0 = (_Float16)g0[j];
                ahi0[j] = h0; alo0[j] = (_Float16)(g0[j] - (float)h0);
                _Float16 h1 = (_Float16)g1[j];
                ahi1[j] = h1; alo1[j] = (_Float16)(g1[j] - (float)h1);
            }
            #pragma unroll
            for (int nt = 0; nt < 8; ++nt) {
                half8 bf = *reinterpret_cast<const half8*>(
                    wfl + (size_t)((nt * 4 + ks) * 64 + lane) * 8);  // coalesced, L2-hot
                acc[nt][0] = __builtin_amdgcn_mfma_f32_16x16x32_f16(ahi0, bf, acc[nt][0], 0, 0, 0);
                acc[nt][0] = __builtin_amdgcn_mfma_f32_16x16x32_f16(alo0, bf, acc[nt][0], 0, 0, 0);
                acc[nt][1] = __builtin_amdgcn_mfma_f32_16x16x32_f16(ahi1, bf, acc[nt][1], 0, 0, 0);
                acc[nt][1] = __builtin_amdgcn_mfma_f32_16x16x32_f16(alo1, bf, acc[nt][1], 0, 0, 0);
            }
        }

        // ---- epilogue in registers: bias + relu + LN + residual into h ----
        float bsv[8], gmv[8], btv[8];
        #pragma unroll
        for (int nt = 0; nt < 8; ++nt) {
            int c = l * D_ + nt * 16 + m;
            bsv[nt] = biases[c]; gmv[nt] = gamma[c]; btv[nt] = beta[c];
        }
        // C layout: col = nt*16 + (lane&15), row = mt*16 + quad*4 + r.
        // A row's 128 cols live in the 16 lanes of one quad -> xor 1,2,4,8.
        #pragma unroll
        for (int mt = 0; mt < 2; ++mt) {
            #pragma unroll
            for (int r = 0; r < 4; ++r) {
                const int mm = mt * 16 + quad * 4 + r;
                float z[8], s = 0.f, s2 = 0.f;
                #pragma unroll
                for (int nt = 0; nt < 8; ++nt) {
                    float zz = fmaxf(acc[nt][mt][r] + bsv[nt], 0.f);
                    z[nt] = zz; s += zz; s2 += zz * zz;
                }
                #pragma unroll
                for (int o = 1; o < 16; o <<= 1) {   // reduce within quad (16 lanes)
                    s  += __shfl_xor(s, o);
                    s2 += __shfl_xor(s2, o);
                }
                if (mm < P_) {
                    float mu  = s * (1.f / 128.f);
                    float var = s2 * (1.f / 128.f) - mu * mu;
                    float rs  = rsqrtf(var + LN_EPS);
                    #pragma unroll
                    for (int nt = 0; nt < 8; ++nt)
                        h_lds[t][mm][nt * 16 + m] += (z[nt] - mu) * rs * gmv[nt] + btv[nt];
                }
            }
        }
        __syncthreads();   // cross-lane h visibility for next layer / store
    }

    // ---- store: out[b,p,d,t0..t0+3] as float4 ----
    {
        float* ob = out + (size_t)b * P_ * D_ * T_ + t0;
        for (int i = tid; i < P_ * D_; i += 256) {
            int p = i >> 7, d = i & 127;
            float4 v;
            v.x = h_lds[0][p][d];
            v.y = h_lds[1][p][d];
            v.z = h_lds[2][p][d];
            v.w = h_lds[3][p][d];
            *reinterpret_cast<float4*>(ob + (size_t)i * T_) = v;
        }
    }
}

extern "C" void kernel_launch(void* const* d_in, const int* in_sizes, int n_in,
                              void* d_out, int out_size, void* d_ws, size_t ws_size,
                              hipStream_t stream) {
    const float* x    = (const float*)d_in[0];
    const float* dist = (const float*)d_in[1];
    const float* w    = (const float*)d_in[2];
    const float* bias = (const float*)d_in[3];
    const float* gam  = (const float*)d_in[4];
    const float* bet  = (const float*)d_in[5];
    float* out = (float*)d_out;
    _Float16* wf = (_Float16*)d_ws;   // 2*8*4*64*8 fp16 = 64KB

    pack_w<<<16, 256, 0, stream>>>(w, wf);
    // b fastest in linear block id -> t-adjacent blocks (delta id = 64 == 0 mod 8)
    // land on the same XCD, sharing the 64B x/out lines in that XCD's L2.
    gcn_mfma<<<dim3(B_, T_ / GT), 256, 0, stream>>>(x, dist, wf, bias, gam, bet, out);
}